// Round 5
// baseline (604.902 us; speedup 1.0000x reference)
//
#include <hip/hip_runtime.h>
#include <hip/hip_bf16.h>
#include <stdint.h>

// B=8192, D=2048, M=8, C=1000; padded: CPAD=1024, NPAD=8192 (n' = c*8 + m)
#define BDIM 8192
#define DDIM 2048
#define MDIM 8
#define CDIM 1000
#define CPAD 1024
#define NPAD 8192

typedef __attribute__((ext_vector_type(8))) short bf16x8;
typedef __attribute__((ext_vector_type(4))) float f32x4;

__device__ __forceinline__ unsigned short f2bf(float f) {
    union { float f; unsigned u; } v; v.f = f;
    unsigned r = v.u + 0x7fffu + ((v.u >> 16) & 1u);   // RNE
    return (unsigned short)(r >> 16);
}

__device__ __forceinline__ void gl_lds16(const void* g, void* l) {
    __builtin_amdgcn_global_load_lds(
        (const __attribute__((address_space(1))) void*)g,
        (__attribute__((address_space(3))) void*)l,
        16, 0, 0);
}

// ---------------- prep: cast x (fp32 -> bf16) ----------------
__global__ void cast_x_kernel(const float4* __restrict__ x, ushort* __restrict__ xb) {
    int i = blockIdx.x * blockDim.x + threadIdx.x;
    float4 v = x[i];
    ushort4 o;
    o.x = f2bf(v.x); o.y = f2bf(v.y); o.z = f2bf(v.z); o.w = f2bf(v.w);
    *(ushort4*)&xb[(size_t)i * 4] = o;
}

// ---- prep: model_weights (M,D,C) -> wb[n'=c*8+m][d], zero-pad c>=1000 ----
__global__ void prep_w(const float* __restrict__ MW, ushort* __restrict__ wb) {
    __shared__ float tile[32][33];
    int m  = blockIdx.z;
    int c0 = blockIdx.x * 32;
    int d0 = blockIdx.y * 32;
    int tx = threadIdx.x, ty = threadIdx.y;
    const float* src = MW + (size_t)m * DDIM * CDIM;
#pragma unroll
    for (int i = 0; i < 4; i++) {
        int d = d0 + ty + i * 8;
        int c = c0 + tx;
        tile[ty + i * 8][tx] = (c < CDIM) ? src[(size_t)d * CDIM + c] : 0.f;
    }
    __syncthreads();
#pragma unroll
    for (int i = 0; i < 4; i++) {
        int c = c0 + ty + i * 8;
        int d = d0 + tx;
        wb[(size_t)(c * 8 + m) * DDIM + d] = f2bf(tile[tx][ty + i * 8]);
    }
}

// ---- prep: resnet_weight (D, 8000) -> rb[n'=c*8+m][d], zero-pad c>=1000 ----
__global__ void prep_r(const float* __restrict__ R, ushort* __restrict__ rb) {
    __shared__ float tile[32][33];
    int m  = blockIdx.z;
    int c0 = blockIdx.x * 32;
    int d0 = blockIdx.y * 32;
    int tx = threadIdx.x, ty = threadIdx.y;
#pragma unroll
    for (int i = 0; i < 4; i++) {
        int d = d0 + ty + i * 8;
        int c = c0 + tx;
        tile[ty + i * 8][tx] = (c < CDIM) ? R[(size_t)d * (MDIM * CDIM) + m * CDIM + c] : 0.f;
    }
    __syncthreads();
#pragma unroll
    for (int i = 0; i < 4; i++) {
        int c = c0 + ty + i * 8;
        int d = d0 + tx;
        rb[(size_t)(c * 8 + m) * DDIM + d] = f2bf(tile[tx][ty + i * 8]);
    }
}

// ---- prep: biases -> interleaved padded float arrays [NPAD] ----
__global__ void prep_bias(const float* __restrict__ mb, const float* __restrict__ rbv,
                          float* __restrict__ mb2, float* __restrict__ rb2) {
    int n = blockIdx.x * 256 + threadIdx.x;   // 0..8191
    int c = n >> 3, m = n & 7;
    mb2[n] = (c < CDIM) ? mb[m * CDIM + c] : 0.f;
    rb2[n] = (c < CDIM) ? rbv[m * CDIM + c] : 0.f;
}

// ---------------- fused dual-B GEMM, 2-barrier/K-step pipeline ----------------
#define BM 256
#define BN 128
#define BK 64
#define NT (DDIM / BK)   // 32

// stage one 16KB unit (128 rows x 64 ushorts), inverse-swizzled global source,
// linear LDS dest (wave-uniform base + lane*16). 2 gl_lds insts per thread.
#define STAGE(G, L) do {                                                       \
    _Pragma("unroll")                                                          \
    for (int it_ = 0; it_ < 2; ++it_) {                                        \
        int ci_ = it_ * 512 + tid;                                             \
        int r_ = ci_ >> 3, cc_ = ci_ & 7;                                      \
        gl_lds16((G) + (size_t)r_ * DDIM + (size_t)((cc_ ^ (r_ & 7)) << 3),    \
                 (L) + (size_t)(it_ * 512 + wbase) * 8);                       \
    }                                                                          \
} while (0)

// H selects a CONTIGUOUS 128-row half (matches the staged unit: U0 = rows
// 0..127, U3 = rows 128..255); wm picks the 64-row half within the unit.
#define LDA(AC, H) do {                                                        \
    _Pragma("unroll")                                                          \
    for (int i_ = 0; i_ < 4; i_++)                                             \
    _Pragma("unroll")                                                          \
    for (int kh_ = 0; kh_ < 2; kh_++) {                                        \
        int row_ = (H) * 128 + wm * 64 + i_ * 16 + (lane & 15);                \
        int cc_ = kh_ * 4 + (lane >> 4);                                       \
        af[i_][kh_] = *(const bf16x8*)&(AC)[row_ * BK + ((cc_ ^ (row_ & 7)) << 3)]; \
    }                                                                          \
} while (0)

#define LDB(BS, BF) do {                                                       \
    _Pragma("unroll")                                                          \
    for (int j_ = 0; j_ < 2; j_++)                                             \
    _Pragma("unroll")                                                          \
    for (int kh_ = 0; kh_ < 2; kh_++) {                                        \
        int row_ = wn * 32 + j_ * 16 + (lane & 15);                            \
        int cc_ = kh_ * 4 + (lane >> 4);                                       \
        BF[j_][kh_] = *(const bf16x8*)&(BS)[row_ * BK + ((cc_ ^ (row_ & 7)) << 3)]; \
    }                                                                          \
} while (0)

#define MM(ACC, H, BF) do {                                                    \
    __builtin_amdgcn_s_setprio(1);                                             \
    _Pragma("unroll")                                                          \
    for (int i_ = 0; i_ < 4; i_++)                                             \
    _Pragma("unroll")                                                          \
    for (int j_ = 0; j_ < 2; j_++)                                             \
    _Pragma("unroll")                                                          \
    for (int kh_ = 0; kh_ < 2; kh_++)                                          \
        ACC[(H) * 4 + i_][j_] = __builtin_amdgcn_mfma_f32_16x16x32_bf16(       \
            af[i_][kh_], BF[j_][kh_], ACC[(H) * 4 + i_][j_], 0, 0, 0);         \
    __builtin_amdgcn_s_setprio(0);                                             \
} while (0)

#define FENCE() asm volatile("" ::: "memory")
#define BARRIER() do { FENCE(); __builtin_amdgcn_s_barrier(); FENCE(); } while (0)
#define WAITV(N) asm volatile("s_waitcnt vmcnt(" #N ")" ::: "memory")

__global__ __launch_bounds__(512, 2) void gemm_fused(
    const ushort* __restrict__ xb, const ushort* __restrict__ wb,
    const ushort* __restrict__ rb,
    const float* __restrict__ mb2, const float* __restrict__ rb2,
    float* __restrict__ out) {
    __shared__ ushort As[2][BM * BK];    // 2 x 32 KB
    __shared__ ushort B1s[2][BN * BK];   // 2 x 16 KB
    __shared__ ushort B2s[2][BN * BK];   // 2 x 16 KB

    int tid   = threadIdx.x;
    int lane  = tid & 63;
    int wid   = tid >> 6;        // 0..7
    int wm    = wid >> 2;        // 0..1 -> 64-row half within each A unit
    int wn    = wid & 3;         // 0..3 -> 32-col quarter
    int wbase = tid & ~63;

    // T1: bijective XCD swizzle (2048 % 8 == 0)
    int wg = blockIdx.x;
    int wgs = (wg & 7) * 256 + (wg >> 3);
    int tile_m = wgs >> 6;       // 0..31
    int tile_n = wgs & 63;       // 0..63
    int brow = tile_m * BM;
    int bn0  = tile_n * BN;

    const ushort* xg  = xb + (size_t)brow * DDIM;
    const ushort* w1g = wb + (size_t)bn0 * DDIM;
    const ushort* w2g = rb + (size_t)bn0 * DDIM;

    f32x4 acc1[8][2] = {};
    f32x4 acc2[8][2] = {};
    bf16x8 af[4][2], bf1[2][2], bf2[2][2];

    // prologue: stage tile 0, unit order = consumption order:
    // U0 = A rows 0..127 (ph0), U1 = B1 (ph0), U2 = B2 (ph1), U3 = A rows 128..255 (ph2)
    STAGE(xg,              As[0]);
    STAGE(w1g,             B1s[0]);
    STAGE(w2g,             B2s[0]);
    STAGE(xg + 128 * DDIM, As[0] + 128 * BK);
    WAITV(4);                 // U0,U1 done; invariant: 4 outstanding at body start
    BARRIER();

    // body invariant at top of iteration t: outstanding = U2,U3(t) [4 insts];
    // U0,U1(t) drained + barrier'd. Last iteration stages in-bounds garbage
    // (tile NT), never consumed.
#pragma unroll 2
    for (int t = 0; t < NT; ++t) {
        int buf = t & 1;
        ushort* Ac  = As[buf];
        ushort* B1c = B1s[buf];
        ushort* B2c = B2s[buf];
        ushort* An  = As[buf ^ 1];
        ushort* B1n = B1s[buf ^ 1];
        ushort* B2n = B2s[buf ^ 1];
        const int kn = (t + 1) * BK;

        // ph0: reads U0,U1(t) | issue ALL stages for t+1 | MFMA acc1 h0
        LDA(Ac, 0);
        LDB(B1c, bf1);
        STAGE(xg + kn,             An);             // U0(t+1)
        STAGE(w1g + kn,            B1n);            // U1(t+1)
        STAGE(w2g + kn,            B2n);            // U2(t+1)
        STAGE(xg + 128 * DDIM + kn, An + 128 * BK); // U3(t+1)
        MM(acc1, 0, bf1);
        WAITV(8);            // drains U2,U3(t) — issued at ph0(t-1), ~4 phases slack
        BARRIER();

        // barrier-free back half: compiler interleaves ds_reads with MFMA
        LDB(B2c, bf2);       // reads U2(t)
        MM(acc2, 0, bf2);
        LDA(Ac, 1);          // reads U3(t)
        MM(acc1, 1, bf1);
        MM(acc2, 1, bf2);
        WAITV(4);            // drains U0,U1(t+1) — issued this body, ~3 phases slack
        BARRIER();           // also WAR gate: buf(t) reads done before t+1 stages buf^1
    }
    WAITV(0);  // don't let garbage-stage DMA outlive this workgroup's LDS

    // ---- epilogue: p = (acc1+b1)(acc2+b2); reduce over m (8 adjacent n');
    // n' = c*8 + m -> 3x shfl_xor; plain stores, disjoint per block.
    // acc rf = H*4+i -> tile row = (rf>>2)*128 + wm*64 + (rf&3)*16 + frag row ----
#pragma unroll
    for (int j = 0; j < 2; j++) {
        int np = bn0 + wn * 32 + j * 16 + (lane & 15);
        float bb1 = mb2[np];
        float bb2 = rb2[np];
        int c = tile_n * 16 + wn * 4 + j * 2 + ((lane >> 3) & 1);
#pragma unroll
        for (int rf = 0; rf < 8; rf++) {
#pragma unroll
            for (int r = 0; r < 4; r++) {
                float p = (acc1[rf][j][r] + bb1) * (acc2[rf][j][r] + bb2);
                p += __shfl_xor(p, 1);
                p += __shfl_xor(p, 2);
                p += __shfl_xor(p, 4);
                if ((lane & 7) == 0 && c < CDIM) {
                    int row = brow + (rf >> 2) * 128 + wm * 64 + (rf & 3) * 16
                              + ((lane >> 4) << 2) + r;
                    out[(size_t)row * CDIM + c] = p;
                }
            }
        }
    }
}

extern "C" void kernel_launch(void* const* d_in, const int* in_sizes, int n_in,
                              void* d_out, int out_size, void* d_ws, size_t ws_size,
                              hipStream_t stream) {
    const float* x   = (const float*)d_in[0];   // [8192][2048]
    const float* mw  = (const float*)d_in[1];   // [8][2048][1000]
    const float* mb  = (const float*)d_in[2];   // [8][1000]
    const float* rw  = (const float*)d_in[3];   // [2048][8000]
    const float* rbv = (const float*)d_in[4];   // [8000]
    float* out = (float*)d_out;                 // [8192][1000]

    char* ws = (char*)d_ws;
    ushort* xb  = (ushort*)ws;                                  // 33,554,432 B
    ushort* wb  = (ushort*)(ws + (size_t)33554432);             // 33,554,432 B
    ushort* rb  = (ushort*)(ws + (size_t)67108864);             // 33,554,432 B
    float*  mb2 = (float*)(ws + (size_t)100663296);             // 32,768 B
    float*  rb2 = (float*)(ws + (size_t)100696064);             // 32,768 B

    cast_x_kernel<<<BDIM * DDIM / (256 * 4), 256, 0, stream>>>((const float4*)x, xb);
    prep_w<<<dim3(CPAD / 32, DDIM / 32, MDIM), dim3(32, 8), 0, stream>>>(mw, wb);
    prep_r<<<dim3(CPAD / 32, DDIM / 32, MDIM), dim3(32, 8), 0, stream>>>(rw, rb);
    prep_bias<<<NPAD / 256, 256, 0, stream>>>(mb, rbv, mb2, rb2);

    gemm_fused<<<dim3((BDIM / BM) * (NPAD / BN)), 512, 0, stream>>>(xb, wb, rb, mb2, rb2, out);
}

// Round 6
// 592.848 us; speedup vs baseline: 1.0203x; 1.0203x over previous
//
#include <hip/hip_runtime.h>
#include <hip/hip_bf16.h>
#include <stdint.h>

// B=8192, D=2048, M=8, C=1000; padded: CPAD=1024, NPAD=8192 (n' = c*8 + m)
#define BDIM 8192
#define DDIM 2048
#define MDIM 8
#define CDIM 1000
#define CPAD 1024
#define NPAD 8192

typedef __attribute__((ext_vector_type(8))) short bf16x8;
typedef __attribute__((ext_vector_type(4))) float f32x4;

__device__ __forceinline__ unsigned short f2bf(float f) {
    union { float f; unsigned u; } v; v.f = f;
    unsigned r = v.u + 0x7fffu + ((v.u >> 16) & 1u);   // RNE
    return (unsigned short)(r >> 16);
}

__device__ __forceinline__ void gl_lds16(const void* g, void* l) {
    __builtin_amdgcn_global_load_lds(
        (const __attribute__((address_space(1))) void*)g,
        (__attribute__((address_space(3))) void*)l,
        16, 0, 0);
}

// ---------------- prep: cast x (fp32 -> bf16) ----------------
__global__ void cast_x_kernel(const float4* __restrict__ x, ushort* __restrict__ xb) {
    int i = blockIdx.x * blockDim.x + threadIdx.x;
    float4 v = x[i];
    ushort4 o;
    o.x = f2bf(v.x); o.y = f2bf(v.y); o.z = f2bf(v.z); o.w = f2bf(v.w);
    *(ushort4*)&xb[(size_t)i * 4] = o;
}

// ---- prep: model_weights (M,D,C) -> wb[n'=c*8+m][d], zero-pad c>=1000 ----
__global__ void prep_w(const float* __restrict__ MW, ushort* __restrict__ wb) {
    __shared__ float tile[32][33];
    int m  = blockIdx.z;
    int c0 = blockIdx.x * 32;
    int d0 = blockIdx.y * 32;
    int tx = threadIdx.x, ty = threadIdx.y;
    const float* src = MW + (size_t)m * DDIM * CDIM;
#pragma unroll
    for (int i = 0; i < 4; i++) {
        int d = d0 + ty + i * 8;
        int c = c0 + tx;
        tile[ty + i * 8][tx] = (c < CDIM) ? src[(size_t)d * CDIM + c] : 0.f;
    }
    __syncthreads();
#pragma unroll
    for (int i = 0; i < 4; i++) {
        int c = c0 + ty + i * 8;
        int d = d0 + tx;
        wb[(size_t)(c * 8 + m) * DDIM + d] = f2bf(tile[tx][ty + i * 8]);
    }
}

// ---- prep: resnet_weight (D, 8000) -> rb[n'=c*8+m][d], zero-pad c>=1000 ----
__global__ void prep_r(const float* __restrict__ R, ushort* __restrict__ rb) {
    __shared__ float tile[32][33];
    int m  = blockIdx.z;
    int c0 = blockIdx.x * 32;
    int d0 = blockIdx.y * 32;
    int tx = threadIdx.x, ty = threadIdx.y;
#pragma unroll
    for (int i = 0; i < 4; i++) {
        int d = d0 + ty + i * 8;
        int c = c0 + tx;
        tile[ty + i * 8][tx] = (c < CDIM) ? R[(size_t)d * (MDIM * CDIM) + m * CDIM + c] : 0.f;
    }
    __syncthreads();
#pragma unroll
    for (int i = 0; i < 4; i++) {
        int c = c0 + ty + i * 8;
        int d = d0 + tx;
        rb[(size_t)(c * 8 + m) * DDIM + d] = f2bf(tile[tx][ty + i * 8]);
    }
}

// ---- prep: biases -> interleaved padded float arrays [NPAD] ----
__global__ void prep_bias(const float* __restrict__ mb, const float* __restrict__ rbv,
                          float* __restrict__ mb2, float* __restrict__ rb2) {
    int n = blockIdx.x * 256 + threadIdx.x;   // 0..8191
    int c = n >> 3, m = n & 7;
    mb2[n] = (c < CDIM) ? mb[m * CDIM + c] : 0.f;
    rb2[n] = (c < CDIM) ? rbv[m * CDIM + c] : 0.f;
}

// ---------------- fused dual-B GEMM, 4-phase kh-split pipeline ----------------
#define BM 256
#define BN 128
#define BK 64
#define NT (DDIM / BK)   // 32

// stage one 16KB unit (128 rows x 64 ushorts), inverse-swizzled global source,
// linear LDS dest (wave-uniform base + lane*16). 2 gl_lds insts per thread.
#define STAGE(G, L) do {                                                       \
    _Pragma("unroll")                                                          \
    for (int it_ = 0; it_ < 2; ++it_) {                                        \
        int ci_ = it_ * 512 + tid;                                             \
        int r_ = ci_ >> 3, cc_ = ci_ & 7;                                      \
        gl_lds16((G) + (size_t)r_ * DDIM + (size_t)((cc_ ^ (r_ & 7)) << 3),    \
                 (L) + (size_t)(it_ * 512 + wbase) * 8);                       \
    }                                                                          \
} while (0)

// load A frags for row-half H (contiguous 128-row staged unit), K-half KH only
#define LDA_K(AC, H, KH) do {                                                  \
    _Pragma("unroll")                                                          \
    for (int i_ = 0; i_ < 4; i_++) {                                           \
        int row_ = (H) * 128 + wm * 64 + i_ * 16 + (lane & 15);                \
        int cc_ = (KH) * 4 + (lane >> 4);                                      \
        af[i_][KH] = *(const bf16x8*)&(AC)[row_ * BK + ((cc_ ^ (row_ & 7)) << 3)]; \
    }                                                                          \
} while (0)

#define LDB_K(BS, BF, KH) do {                                                 \
    _Pragma("unroll")                                                          \
    for (int j_ = 0; j_ < 2; j_++) {                                           \
        int row_ = wn * 32 + j_ * 16 + (lane & 15);                            \
        int cc_ = (KH) * 4 + (lane >> 4);                                      \
        BF[j_][KH] = *(const bf16x8*)&(BS)[row_ * BK + ((cc_ ^ (row_ & 7)) << 3)]; \
    }                                                                          \
} while (0)

// 8 MFMA: one (acc, H, KH) cluster
#define MMK(ACC, H, BF, KH) do {                                               \
    _Pragma("unroll")                                                          \
    for (int i_ = 0; i_ < 4; i_++)                                             \
    _Pragma("unroll")                                                          \
    for (int j_ = 0; j_ < 2; j_++)                                             \
        ACC[(H) * 4 + i_][j_] = __builtin_amdgcn_mfma_f32_16x16x32_bf16(       \
            af[i_][KH], BF[j_][KH], ACC[(H) * 4 + i_][j_], 0, 0, 0);           \
} while (0)

#define FENCE() asm volatile("" ::: "memory")
#define BARRIER() do { FENCE(); __builtin_amdgcn_s_barrier(); FENCE(); } while (0)
#define WAITV(N) asm volatile("s_waitcnt vmcnt(" #N ")" ::: "memory")
#define SP1() __builtin_amdgcn_s_setprio(1)
#define SP0() __builtin_amdgcn_s_setprio(0)

__global__ __launch_bounds__(512, 2) void gemm_fused(
    const ushort* __restrict__ xb, const ushort* __restrict__ wb,
    const ushort* __restrict__ rb,
    const float* __restrict__ mb2, const float* __restrict__ rb2,
    float* __restrict__ out) {
    __shared__ ushort As[2][BM * BK];    // 2 x 32 KB
    __shared__ ushort B1s[2][BN * BK];   // 2 x 16 KB
    __shared__ ushort B2s[2][BN * BK];   // 2 x 16 KB

    int tid   = threadIdx.x;
    int lane  = tid & 63;
    int wid   = tid >> 6;        // 0..7
    int wm    = wid >> 2;        // 0..1 -> 64-row half within each A unit
    int wn    = wid & 3;         // 0..3 -> 32-col quarter
    int wbase = tid & ~63;

    // T1: bijective XCD swizzle (2048 % 8 == 0)
    int wg = blockIdx.x;
    int wgs = (wg & 7) * 256 + (wg >> 3);
    int tile_m = wgs >> 6;       // 0..31
    int tile_n = wgs & 63;       // 0..63
    int brow = tile_m * BM;
    int bn0  = tile_n * BN;

    const ushort* xg  = xb + (size_t)brow * DDIM;
    const ushort* w1g = wb + (size_t)bn0 * DDIM;
    const ushort* w2g = rb + (size_t)bn0 * DDIM;

    f32x4 acc1[8][2] = {};
    f32x4 acc2[8][2] = {};
    bf16x8 af[4][2], bf1[2][2], bf2[2][2];

    // Units: U0 = A rows 0..127, U1 = B1, U2 = B2, U3 = A rows 128..255.
    // Prologue: stage U0..U3(0) + U0(1); invariant at K-tile top:
    // outstanding = {U3(t), U0(t+1)} = 4 insts, everything older drained+barrier'd.
    STAGE(xg,               As[0]);              // U0(0)
    STAGE(w1g,              B1s[0]);             // U1(0)
    STAGE(w2g,              B2s[0]);             // U2(0)
    STAGE(xg + 128 * DDIM,  As[0] + 128 * BK);   // U3(0)
    STAGE(xg + BK,          As[1]);              // U0(1)
    WAITV(4);                 // drains U0,U1,U2(0); leaves {U3(0), U0(1)}
    BARRIER();

    // Per K-tile: 4 phases, each {<=8 ds_reads, 1 stage-unit, barrier,
    // 16 MFMA (setprio-wrapped), [counted drain], barrier}.
    // Stage map: P1->U1(t+1), P2->U2(t+1), P3->U3(t+1), P4->U0(t+2).
    // Drains: end-P2 WAITV(4) [U3(t),U0(t+1)]; end-P4 WAITV(4) [U1,U2(t+1)].
    // Tail iterations stage in-bounds garbage (never consumed).
#pragma unroll 2
    for (int t = 0; t < NT; ++t) {
        int buf = t & 1;
        ushort* Ac  = As[buf];
        ushort* B1c = B1s[buf];
        ushort* B2c = B2s[buf];
        ushort* An  = As[buf ^ 1];
        ushort* B1n = B1s[buf ^ 1];
        ushort* B2n = B2s[buf ^ 1];
        const int kn  = (t + 1) * BK;
        const int kn2 = (t + 2) * BK;

        // P1: kh0 reads (af-h0:4, bf1:2, bf2:2) | stage U1(t+1) | 16 MFMA kh0 h0
        LDA_K(Ac, 0, 0);
        LDB_K(B1c, bf1, 0);
        LDB_K(B2c, bf2, 0);
        STAGE(w1g + kn, B1n);
        BARRIER();
        SP1(); MMK(acc1, 0, bf1, 0); MMK(acc2, 0, bf2, 0); SP0();
        BARRIER();

        // P2: kh1 reads (af-h0:4, bf1:2, bf2:2) | stage U2(t+1) | 16 MFMA kh1 h0
        LDA_K(Ac, 0, 1);
        LDB_K(B1c, bf1, 1);
        LDB_K(B2c, bf2, 1);
        STAGE(w2g + kn, B2n);
        SP1(); // raise before drain so we resume quickly
        WAITV(4);            // drains U3(t) [P3 reads], U0(t+1) [next P1 reads]
        BARRIER();
        MMK(acc1, 0, bf1, 1); MMK(acc2, 0, bf2, 1); SP0();
        BARRIER();

        // P3: af-h1 both kh (8 reads) | stage U3(t+1) | 16 MFMA acc1 h1
        LDA_K(Ac, 1, 0);
        LDA_K(Ac, 1, 1);
        STAGE(xg + 128 * DDIM + kn, An + 128 * BK);
        BARRIER();
        SP1(); MMK(acc1, 1, bf1, 0); MMK(acc1, 1, bf1, 1); SP0();
        BARRIER();

        // P4: no reads | stage U0(t+2) into As[buf] (tile-t reads all done) | acc2 h1
        STAGE(xg + kn2, Ac);
        BARRIER();
        SP1(); MMK(acc2, 1, bf2, 0); MMK(acc2, 1, bf2, 1);
        WAITV(4);            // drains U1,U2(t+1) [next P1/P2 read them]
        SP0();
        BARRIER();
    }
    WAITV(0);  // garbage-stage DMA must not outlive this workgroup's LDS

    // ---- epilogue: p = (acc1+b1)(acc2+b2); reduce over m (8 adjacent n');
    // n' = c*8 + m -> 3x shfl_xor; plain stores, disjoint per block.
    // acc rf = H*4+i -> tile row = (rf>>2)*128 + wm*64 + (rf&3)*16 + frag row ----
#pragma unroll
    for (int j = 0; j < 2; j++) {
        int np = bn0 + wn * 32 + j * 16 + (lane & 15);
        float bb1 = mb2[np];
        float bb2 = rb2[np];
        int c = tile_n * 16 + wn * 4 + j * 2 + ((lane >> 3) & 1);
#pragma unroll
        for (int rf = 0; rf < 8; rf++) {
#pragma unroll
            for (int r = 0; r < 4; r++) {
                float p = (acc1[rf][j][r] + bb1) * (acc2[rf][j][r] + bb2);
                p += __shfl_xor(p, 1);
                p += __shfl_xor(p, 2);
                p += __shfl_xor(p, 4);
                if ((lane & 7) == 0 && c < CDIM) {
                    int row = brow + (rf >> 2) * 128 + wm * 64 + (rf & 3) * 16
                              + ((lane >> 4) << 2) + r;
                    out[(size_t)row * CDIM + c] = p;
                }
            }
        }
    }
}

extern "C" void kernel_launch(void* const* d_in, const int* in_sizes, int n_in,
                              void* d_out, int out_size, void* d_ws, size_t ws_size,
                              hipStream_t stream) {
    const float* x   = (const float*)d_in[0];   // [8192][2048]
    const float* mw  = (const float*)d_in[1];   // [8][2048][1000]
    const float* mb  = (const float*)d_in[2];   // [8][1000]
    const float* rw  = (const float*)d_in[3];   // [2048][8000]
    const float* rbv = (const float*)d_in[4];   // [8000]
    float* out = (float*)d_out;                 // [8192][1000]

    char* ws = (char*)d_ws;
    ushort* xb  = (ushort*)ws;                                  // 33,554,432 B
    ushort* wb  = (ushort*)(ws + (size_t)33554432);             // 33,554,432 B
    ushort* rb  = (ushort*)(ws + (size_t)67108864);             // 33,554,432 B
    float*  mb2 = (float*)(ws + (size_t)100663296);             // 32,768 B
    float*  rb2 = (float*)(ws + (size_t)100696064);             // 32,768 B

    cast_x_kernel<<<BDIM * DDIM / (256 * 4), 256, 0, stream>>>((const float4*)x, xb);
    prep_w<<<dim3(CPAD / 32, DDIM / 32, MDIM), dim3(32, 8), 0, stream>>>(mw, wb);
    prep_r<<<dim3(CPAD / 32, DDIM / 32, MDIM), dim3(32, 8), 0, stream>>>(rw, rb);
    prep_bias<<<NPAD / 256, 256, 0, stream>>>(mb, rbv, mb2, rb2);

    gemm_fused<<<dim3((BDIM / BM) * (NPAD / BN)), 512, 0, stream>>>(xb, wb, rb, mb2, rb2, out);
}